// Round 2
// 1208.776 us; speedup vs baseline: 1.0313x; 1.0313x over previous
//
#include <hip/hip_runtime.h>
#include <stdint.h>

// ---- types -----------------------------------------------------------------
typedef __bf16 bf16x8 __attribute__((ext_vector_type(8)));
typedef float floatx4 __attribute__((ext_vector_type(4)));

#define MFMA16(a, b, c) __builtin_amdgcn_mfma_f32_16x16x32_bf16((a), (b), (c), 0, 0, 0)

// RNE float->bf16, packed pair into a dword
__device__ __forceinline__ uint32_t pack2bf(float a, float b) {
  uint32_t ua = __builtin_bit_cast(uint32_t, a);
  uint32_t ub = __builtin_bit_cast(uint32_t, b);
  ua = (ua + 0x7fffu + ((ua >> 16) & 1u)) >> 16;
  ub = (ub + 0x7fffu + ((ub >> 16) & 1u)) >> 16;
  return ua | (ub << 16);
}

// async global->LDS, 16B per lane; LDS dest is wave-uniform base + lane*16
__device__ __forceinline__ void gload16(uint16_t* lds, const uint16_t* g) {
  __builtin_amdgcn_global_load_lds(
      (const __attribute__((address_space(1))) void*)g,
      (__attribute__((address_space(3))) void*)lds, 16, 0, 0);
}

// ---- problem constants -----------------------------------------------------
#define NN 8192   // nodes
#define DD 256    // feature dim
#define PP 3      // adjacency powers

// ============================================================================
// Kernel 1: X (8192x256 f32) -> XTs: bf16 in GEMM-staging order.
// Layout: [kt(128)][tile(32)][lane(64)][8 elems], tile = ks*16 + nt,
// element j of (kt,ks,nt,lane) = X[kt*64 + ks*32 + (lane>>4)*8 + j][nt*16+(lane&15)].
// This is exactly the ldsB image k_gemm_ax wants, so staging there is pure
// global_load_lds with linear addresses (rule #21: linear dest + pre-swizzled src).
// Grid (128 kt, 2 d-halves).
// ============================================================================
__global__ __launch_bounds__(256) void k_transpose_x(const float* __restrict__ X,
                                                     uint16_t* __restrict__ XTs) {
  __shared__ float lds[64][133];  // 64 k-rows x 128 d-cols (+5 pad: spreads banks)
  const int kt = blockIdx.x;
  const int half = blockIdx.y;
  const int t = threadIdx.x;
#pragma unroll
  for (int j = 0; j < 8; ++j) {
    int idx = t + 256 * j;        // 0..2047
    int m = idx >> 5;             // 0..63
    int c = (idx & 31) << 2;      // 0..124
    float4 v = *(const float4*)(X + (size_t)(kt * 64 + m) * DD + half * 128 + c);
    lds[m][c] = v.x; lds[m][c + 1] = v.y; lds[m][c + 2] = v.z; lds[m][c + 3] = v.w;
  }
  __syncthreads();
#pragma unroll
  for (int j = 0; j < 4; ++j) {
    int slot = t + 256 * j;       // 0..1023
    int tl = slot >> 6;           // 0..15 local tile
    int lane = slot & 63;
    int ks = tl >> 3, ntl = tl & 7;
    int q = lane >> 4, dl = ntl * 16 + (lane & 15);
    int kb = ks * 32 + q * 8;
    uint32_t w0 = pack2bf(lds[kb + 0][dl], lds[kb + 1][dl]);
    uint32_t w1 = pack2bf(lds[kb + 2][dl], lds[kb + 3][dl]);
    uint32_t w2 = pack2bf(lds[kb + 4][dl], lds[kb + 5][dl]);
    uint32_t w3 = pack2bf(lds[kb + 6][dl], lds[kb + 7][dl]);
    int tile = ks * 16 + half * 8 + ntl;
    *(uint4*)(XTs + (((size_t)kt * 32 + tile) * 64 + lane) * 8) = make_uint4(w0, w1, w2, w3);
  }
}

// ============================================================================
// Kernel 2: W (3x256x256 f32) -> WcatT (256x768 bf16): WcatT[d][r*256+e]=W[r][d][e]
// ============================================================================
__global__ __launch_bounds__(256) void k_build_wcat(const float* __restrict__ W,
                                                    uint16_t* __restrict__ WcatT) {
  int idx = blockIdx.x * 256 + threadIdx.x;  // one task = 4 output elems
  int o = idx * 4;                           // 0..196604
  int d = o / 768;
  int c = o - d * 768;
  int r = c >> 8;
  int e = c & 255;
  float4 v = *(const float4*)(W + (size_t)r * DD * DD + (size_t)d * DD + e);
  *(uint2*)(WcatT + o) = make_uint2(pack2bf(v.x, v.y), pack2bf(v.z, v.w));
}

// ============================================================================
// Kernel 3: M[p] = A[p] @ X.  BM=64, BN=256 (full width -> A read exactly once),
// BK=64 (32 MFMA/wave per barrier pair).  grid = (128 row-tiles, 3 p), 256 thr.
// X staged via global_load_lds dwordx4 from pre-swizzled XTs (no VALU, no regs).
// A staged via reg-load f32 -> pack2bf -> ds_write_b128 (fused conversion).
// Frag-major LDS: slot = tile*64 + lane, 8 bf16/lane -> lane-contiguous b128.
// ============================================================================
__global__ __launch_bounds__(256) void k_gemm_ax(const float* __restrict__ A,
                                                 const uint16_t* __restrict__ XTs,
                                                 float* __restrict__ M) {
  __shared__ uint16_t ldsA[8 * 64 * 8];    // 64(m) x 64(k) bf16, frag-major, 8KB
  __shared__ uint16_t ldsB[32 * 64 * 8];   // 64(k) x 256(n) bf16, frag-major, 32KB

  const int t = threadIdx.x;
  const int lane = t & 63;
  const int wid = t >> 6;
  const int wm = wid >> 1;   // 0..1: rows wm*32 .. +32
  const int wn = wid & 1;    // 0..1: cols wn*128 .. +128
  const int rt = blockIdx.x; // row tile (64 rows)
  const int p = blockIdx.y;

  const float* Ap = A + (size_t)p * NN * NN + (size_t)rt * 64 * NN;
  float* Mp = M + (size_t)p * NN * DD;

  // A staging task: thread t -> row arow, 16 consecutive k at a8*16 (two 8-groups)
  const int arow = t >> 2;   // 0..63
  const int a8 = t & 3;
  const float4* asrc = (const float4*)(Ap + (size_t)arow * NN + a8 * 16);
  // 8-group g covers k=g*8..+8; g0=a8*2, g1=a8*2+1. tile=(g>>2)*4+(arow>>4),
  // lane=((g&3)<<4)|(arow&15). g1 is g0's lane+16 -> +128 elems.
  const int alds0 = ((((a8 >> 1) * 4 + (arow >> 4)) * 64) +
                     ((((a8 & 1) * 2) << 4) | (arow & 15))) * 8;

  floatx4 acc[2][8];
#pragma unroll
  for (int i = 0; i < 2; ++i)
#pragma unroll
    for (int j = 0; j < 8; ++j) acc[i][j] = (floatx4){0.f, 0.f, 0.f, 0.f};

  for (int kt = 0; kt < 128; ++kt) {
    // A global loads issued early (overlap with prev compute)
    float4 a0 = asrc[0], a1 = asrc[1], a2 = asrc[2], a3 = asrc[3];
    asrc += 16;  // advance 64 floats

    __syncthreads();  // previous iter's LDS reads done

    // X: 8 async 1KB chunks per wave, linear src, linear dest
    const uint16_t* xb = XTs + ((size_t)kt * 32 + wid * 8) * 512 + lane * 8;
#pragma unroll
    for (int i = 0; i < 8; ++i)
      gload16(&ldsB[(wid * 8 + i) * 512], xb + i * 512);

    // A: convert + store (two 8-groups)
    uint4 w;
    w.x = pack2bf(a0.x, a0.y); w.y = pack2bf(a0.z, a0.w);
    w.z = pack2bf(a1.x, a1.y); w.w = pack2bf(a1.z, a1.w);
    *(uint4*)&ldsA[alds0] = w;
    w.x = pack2bf(a2.x, a2.y); w.y = pack2bf(a2.z, a2.w);
    w.z = pack2bf(a3.x, a3.y); w.w = pack2bf(a3.z, a3.w);
    *(uint4*)&ldsA[alds0 + 128] = w;

    __syncthreads();  // drains vmcnt (gload_lds) + lgkm: staging visible

#pragma unroll
    for (int ks = 0; ks < 2; ++ks) {
      bf16x8 af0 = *(const bf16x8*)&ldsA[((ks * 4 + wm * 2 + 0) * 64 + lane) * 8];
      bf16x8 af1 = *(const bf16x8*)&ldsA[((ks * 4 + wm * 2 + 1) * 64 + lane) * 8];
#pragma unroll
      for (int j = 0; j < 8; ++j) {
        bf16x8 bf = *(const bf16x8*)&ldsB[((ks * 16 + wn * 8 + j) * 64 + lane) * 8];
        acc[0][j] = MFMA16(af0, bf, acc[0][j]);
        acc[1][j] = MFMA16(af1, bf, acc[1][j]);
      }
    }
  }

  // epilogue: C/D layout col=lane&15, row=(lane>>4)*4+reg  (m89-verified)
  const int quad = lane >> 4;
  const int cl = lane & 15;
#pragma unroll
  for (int i = 0; i < 2; ++i) {
    int rbase = rt * 64 + wm * 32 + i * 16 + quad * 4;
#pragma unroll
    for (int j = 0; j < 8; ++j) {
      int c = wn * 128 + j * 16 + cl;
#pragma unroll
      for (int r = 0; r < 4; ++r)
        Mp[(size_t)(rbase + r) * DD + c] = acc[i][j][r];
    }
  }
}

// ============================================================================
// Kernel 4: fused Volterra epilogue.  Block = 32 rows x 256 cols, grid 256.
// cat = [X | S1 | S2] (32 x 768) staged bf16 in frag-major LDS; GEMM vs WcatT
// (B-frags straight from global/L2); + bias, relu, store f32.
// ============================================================================
__global__ __launch_bounds__(256) void k_stage3(const float* __restrict__ X,
                                                const float* __restrict__ M,
                                                const uint16_t* __restrict__ WcatT,
                                                const float* __restrict__ b,
                                                float* __restrict__ out) {
  __shared__ uint16_t cat[48 * 64 * 8];  // 24 kt x 2 mt x 64 lanes x 8 bf16 = 48KB
  const int row0 = blockIdx.x * 32;
  const int t = threadIdx.x;
  const float* M0 = M;
  const float* M1 = M + (size_t)NN * DD;
  const float* M2 = M + 2 * (size_t)NN * DD;

#pragma unroll
  for (int j = 0; j < 8; ++j) {
    int idx = t + 256 * j;       // 0..2047
    int m = idx >> 6;            // 0..31
    int e = (idx & 63) << 2;     // 0..252
    size_t off = (size_t)(row0 + m) * DD + e;
    float4 xv = *(const float4*)(X + off);
    float4 a = *(const float4*)(M0 + off);
    float4 bb = *(const float4*)(M1 + off);
    float4 cc = *(const float4*)(M2 + off);
    float4 s1, s2;
    s1.x = a.x + bb.x + cc.x;
    s1.y = a.y + bb.y + cc.y;
    s1.z = a.z + bb.z + cc.z;
    s1.w = a.w + bb.w + cc.w;
    s2.x = a.x * a.x + bb.x * bb.x + cc.x * cc.x + a.x * bb.x + a.x * cc.x + bb.x * cc.x;
    s2.y = a.y * a.y + bb.y * bb.y + cc.y * cc.y + a.y * bb.y + a.y * cc.y + bb.y * cc.y;
    s2.z = a.z * a.z + bb.z * bb.z + cc.z * cc.z + a.z * bb.z + a.z * cc.z + bb.z * cc.z;
    s2.w = a.w * a.w + bb.w * bb.w + cc.w * cc.w + a.w * bb.w + a.w * cc.w + bb.w * cc.w;
#pragma unroll
    for (int part = 0; part < 3; ++part) {
      int k = part * 256 + e;
      int kt = k >> 5;
      int q = (k >> 3) & 3;
      int slot = (kt * 2 + (m >> 4)) * 64 + ((q << 4) | (m & 15));
      float4 v = (part == 0) ? xv : ((part == 1) ? s1 : s2);
      *(uint2*)&cat[slot * 8 + (k & 7)] = make_uint2(pack2bf(v.x, v.y), pack2bf(v.z, v.w));
    }
  }
  __syncthreads();

  const int lane = t & 63;
  const int w = t >> 6;      // wave -> 64 cols
  const int cl = lane & 15;
  const int quad = lane >> 4;
  floatx4 acc[2][4];
#pragma unroll
  for (int i = 0; i < 2; ++i)
#pragma unroll
    for (int j = 0; j < 4; ++j) acc[i][j] = (floatx4){0.f, 0.f, 0.f, 0.f};

  for (int kt = 0; kt < 24; ++kt) {
    bf16x8 af0 = *(const bf16x8*)&cat[((kt * 2 + 0) * 64 + lane) * 8];
    bf16x8 af1 = *(const bf16x8*)&cat[((kt * 2 + 1) * 64 + lane) * 8];
#pragma unroll
    for (int j = 0; j < 4; ++j) {
      int d = w * 64 + j * 16 + cl;
      bf16x8 bv = *(const bf16x8*)(WcatT + (size_t)d * 768 + kt * 32 + quad * 8);
      acc[0][j] = MFMA16(af0, bv, acc[0][j]);
      acc[1][j] = MFMA16(af1, bv, acc[1][j]);
    }
  }

#pragma unroll
  for (int j = 0; j < 4; ++j) {
    int d = w * 64 + j * 16 + cl;
    float bias = b[d] + 3.0f * b[256 + d] + 6.0f * b[512 + d];
#pragma unroll
    for (int mt = 0; mt < 2; ++mt) {
      int rbase = row0 + mt * 16 + quad * 4;
#pragma unroll
      for (int r = 0; r < 4; ++r) {
        float v = acc[mt][j][r] + bias;
        out[(size_t)(rbase + r) * DD + d] = v > 0.f ? v : 0.f;
      }
    }
  }
}

// ============================================================================
// launch
// ============================================================================
extern "C" void kernel_launch(void* const* d_in, const int* in_sizes, int n_in,
                              void* d_out, int out_size, void* d_ws, size_t ws_size,
                              hipStream_t stream) {
  const float* X = (const float*)d_in[0];
  const float* A = (const float*)d_in[1];
  const float* W = (const float*)d_in[2];
  const float* b = (const float*)d_in[3];
  float* out = (float*)d_out;

  char* ws = (char*)d_ws;
  uint16_t* XT = (uint16_t*)ws;                               // 4 MB (swizzled)
  uint16_t* WcatT = (uint16_t*)(ws + 4194304);                // 384 KB
  float* M = (float*)(ws + 4194304 + 393216);                 // 24 MB

  hipLaunchKernelGGL(k_transpose_x, dim3(128, 2), dim3(256), 0, stream, X, XT);
  hipLaunchKernelGGL(k_build_wcat, dim3(192), dim3(256), 0, stream, W, WcatT);
  hipLaunchKernelGGL(k_gemm_ax, dim3(NN / 64, PP), dim3(256), 0, stream, A, XT, M);
  hipLaunchKernelGGL(k_stage3, dim3(NN / 32), dim3(256), 0, stream, X, M, WcatT, b, out);
}